// Round 13
// baseline (177.400 us; speedup 1.0000x reference)
//
#include <hip/hip_runtime.h>
#include <math.h>

#define N_DIM 1024
#define G_DIM 4096
#define B_DIM 2048
#define K2DIM 2048  // 2*N (real|imag concatenated K)
#define CAP 256     // per-row candidate capacity

typedef __attribute__((ext_vector_type(8))) short bf16x8;
typedef __attribute__((ext_vector_type(16))) float f32x16;
typedef unsigned short ushort_t;

// ---------- ws layout (bytes) ----------
#define WS_PRBF  0u                      // bf16 [G][1024]   8 MB
#define WS_PIBF  (8u << 20)              // bf16 [G][1024]   8 MB
#define WS_HBF   (16u << 20)             // bf16 [B][2048]   8 MB ([Hr | -Hi])
#define WS_ROWMAX (24u << 20)            // u32 [B] (8 KB)
#define WS_CCNT  (WS_ROWMAX + 8192u)     // int [B] (8 KB)
#define WS_CAND  (WS_CCNT + 8192u)       // int2 [B][CAP] (4 MB)
#define WS_WG    (WS_CAND + 2048u*CAP*8u)
#define WS_WXR   (WS_WG + 8192u)
#define WS_WXI   (WS_WXR + 8192u)

__device__ __forceinline__ unsigned short f2bf(float f) {
  unsigned u = __float_as_uint(f);
  unsigned r = u + 0x7fffu + ((u >> 16) & 1u);
  return (unsigned short)(r >> 16);
}
__device__ __forceinline__ float bf2f(unsigned short u) {
  return __uint_as_float(((unsigned)u) << 16);
}
__device__ __forceinline__ bf16x8 negbf(bf16x8 v) {
  union { bf16x8 b; uint4 u; } x;
  x.b = v;
  x.u.x ^= 0x80008000u; x.u.y ^= 0x80008000u;
  x.u.z ^= 0x80008000u; x.u.w ^= 0x80008000u;
  return x.b;
}
// fast tanh via v_exp_f32 (alpha in [0,1) -> no overflow concerns)
__device__ __forceinline__ float tanh_fast(float x) {
  const float t = __expf(2.0f * x);
  return __fdividef(t - 1.0f, t + 1.0f);
}

__device__ __forceinline__ void gload_lds16(const void* gsrc, void* ldst) {
  __builtin_amdgcn_global_load_lds(
      (const __attribute__((address_space(1))) void*)gsrc,
      (__attribute__((address_space(3))) void*)ldst, 16, 0, 0);
}

// ---------- K1: fused PSI generation + H conversion + counters zero ----------
__global__ __launch_bounds__(256) void k_prep(
    const float* __restrict__ theta, const float* __restrict__ alpha,
    const float* __restrict__ H,
    float* __restrict__ prT, float* __restrict__ piT,
    ushort_t* __restrict__ prBf, ushort_t* __restrict__ piBf,
    ushort_t* __restrict__ hbf, int4* __restrict__ zeroRegion) {
  __shared__ float sp[32][33], si[32][33];
  const int bid = blockIdx.x, tid = threadIdx.x;
  if (bid < 4096) {
    // PSI part: transpose [N][G] -> [G][N], write f32 + bf16
    const int tx = tid & 31, ty = tid >> 5;
    const int g0 = (bid & 127) * 32, n0 = (bid >> 7) * 32;
    for (int rr = ty; rr < 32; rr += 8) {
      const size_t idx = (size_t)(n0 + rr) * G_DIM + g0 + tx;
      const float a = tanh_fast(alpha[idx]) * 0.03125f;  // 1/sqrt(1024)
      const float th = theta[idx];
      sp[rr][tx] = a * __cosf(th);
      si[rr][tx] = a * __sinf(th);
    }
    __syncthreads();
    for (int rr = ty; rr < 32; rr += 8) {
      const int g = g0 + rr, n = n0 + tx;
      const float pr = sp[tx][rr], pi = si[tx][rr];
      prT[(size_t)g * N_DIM + n] = pr;
      piT[(size_t)g * N_DIM + n] = pi;
      prBf[(size_t)g * N_DIM + n] = f2bf(pr);
      piBf[(size_t)g * N_DIM + n] = f2bf(pi);
    }
  } else {
    if (bid == 4096) {
      // zero rowmax + ccnt (16 KB contiguous = 1024 int4)
      const int4 z = make_int4(0, 0, 0, 0);
      zeroRegion[tid] = z;
      zeroRegion[tid + 256] = z;
      zeroRegion[tid + 512] = z;
      zeroRegion[tid + 768] = z;
    }
    // H -> bf16, layout [B][2048] = [Hr | -Hi]
    const int j4 = ((bid - 4096) * 256 + tid) * 4;
    const int b = j4 >> 11, k = j4 & 2047, c = k >> 10, n = k & 1023;
    float4 v = *reinterpret_cast<const float4*>(
        H + (size_t)c * (B_DIM * N_DIM) + (size_t)b * N_DIM + n);
    if (c) { v.x = -v.x; v.y = -v.y; v.z = -v.z; v.w = -v.w; }
    ushort4 u;
    u.x = f2bf(v.x); u.y = f2bf(v.y); u.z = f2bf(v.z); u.w = f2bf(v.w);
    *reinterpret_cast<ushort4*>(hbf + j4) = u;
  }
}

#define LGKM(n) asm volatile("s_waitcnt lgkmcnt(" #n ")" ::: "memory")
#define SB0() __builtin_amdgcn_sched_barrier(0)

// ---------- K2: merged-B 32x32x16 dual-acc GEMM -> rowmax + candidates ----
// Best-measured core (R10 bench, 62.8us): BM=256, BN=128, merged 32 k-lo +
// 32 k-hi. 8 waves 4M x 2N. LDS 2-ring x 48KB = 96KB; slot ^= row&7.
// accr = aL*pr + aH*pi ; acci = aL*pi + aH*(-pr)   (aH = -Hi)
// Fused epilogue: per-row shfl-max, global atomicMax rowmax, superset
// candidate append (xab >= waveLocalRowMax - 0.25).
__global__ __launch_bounds__(512, 2) void k_gemm(
    const ushort_t* __restrict__ hbf, const ushort_t* __restrict__ prBf,
    const ushort_t* __restrict__ piBf, unsigned* __restrict__ rowmax,
    int* __restrict__ ccnt, int2* __restrict__ cand) {
  __shared__ ushort_t smem[49152];     // 96 KB: 2 bufs x 24576 ushorts
  const int tid = threadIdx.x;
  const int l = tid & 63, w = tid >> 6;
  const int wm = w >> 1, wn = w & 1;   // 4M x 2N
  const int bid = blockIdx.x;
  const int xcd = bid & 7, idx = bid >> 3;
  const int g0 = (xcd * 4 + (idx & 3)) * 128;
  const int b0 = (idx >> 2) * 256;

  // fragment offsets: rows 64 ushorts (128 B), slot ^= row&7 (row&7 == l&7)
  const int h = l >> 5;
  int colL[2], colH[2];
#pragma unroll
  for (int ks = 0; ks < 2; ++ks) {
    colL[ks] = ((ks * 2 + h) ^ (l & 7)) * 8;
    colH[ks] = ((4 + ks * 2 + h) ^ (l & 7)) * 8;
  }
  int rowA[2], rowB[2];
#pragma unroll
  for (int mi = 0; mi < 2; ++mi) rowA[mi] = (wm * 64 + mi * 32 + (l & 31)) * 64;
#pragma unroll
  for (int ni = 0; ni < 2; ++ni) rowB[ni] = 16384 + (wn * 64 + ni * 32 + (l & 31)) * 64;

  // staging: linear LDS dest, inverse-swizzled global source
  const int rT = tid >> 3, sd = tid & 7, sl = sd ^ (rT & 7);
  const ushort_t* srcA = hbf + (sl < 4 ? sl * 8 : 1024 + (sl - 4) * 8);
  const ushort_t* srcB = (sl < 4) ? (prBf + sl * 8) : (piBf + (sl - 4) * 8);
  const int dBase = (tid & ~63) * 8;

  f32x16 accr[2][2], acci[2][2];
#pragma unroll
  for (int mi = 0; mi < 2; ++mi)
#pragma unroll
    for (int ni = 0; ni < 2; ++ni) {
      accr[mi][ni] = (f32x16)(0.f);
      acci[mi][ni] = (f32x16)(0.f);
    }

  // prologue: stage tile 0 into buf 0
#pragma unroll
  for (int i = 0; i < 4; ++i)
    gload_lds16(srcA + (size_t)(b0 + i * 64 + rT) * K2DIM, (void*)(smem + i * 4096 + dBase));
#pragma unroll
  for (int i = 0; i < 2; ++i)
    gload_lds16(srcB + (size_t)(g0 + i * 64 + rT) * N_DIM, (void*)(smem + 16384 + i * 4096 + dBase));
  asm volatile("s_waitcnt vmcnt(0)" ::: "memory");
  __builtin_amdgcn_s_barrier();

  bf16x8 aL[2][2], aH[2][2], prB[2][2], piB[2][2], prN[2][2];

  // pre-read aL + prB of tile 0
  {
    const ushort_t* buf = smem;
#pragma unroll
    for (int mi = 0; mi < 2; ++mi)
#pragma unroll
      for (int ks = 0; ks < 2; ++ks)
        aL[mi][ks] = *(const bf16x8*)&buf[rowA[mi] + colL[ks]];
#pragma unroll
    for (int ni = 0; ni < 2; ++ni)
#pragma unroll
      for (int ks = 0; ks < 2; ++ks)
        prB[ni][ks] = *(const bf16x8*)&buf[rowB[ni] + colL[ks]];
  }

  for (int t = 0; t < 32; ++t) {
    const ushort_t* buf = smem + (t & 1) * 24576;
    const int nb = ((t + 1) & 1) * 24576;
    const int kp = (t + 1) * 32;
    const bool pf = (t < 31);

    // ---- P0: read piB; stage A(0,1); S0: accr += aL*pr
#pragma unroll
    for (int ni = 0; ni < 2; ++ni)
#pragma unroll
      for (int ks = 0; ks < 2; ++ks)
        piB[ni][ks] = *(const bf16x8*)&buf[rowB[ni] + colH[ks]];
    if (pf) {
#pragma unroll
      for (int i = 0; i < 2; ++i)
        gload_lds16(srcA + (size_t)(b0 + i * 64 + rT) * K2DIM + kp,
                    (void*)(smem + nb + i * 4096 + dBase));
    }
    LGKM(4); SB0();
    __builtin_amdgcn_s_setprio(1);
#pragma unroll
    for (int mi = 0; mi < 2; ++mi)
#pragma unroll
      for (int ni = 0; ni < 2; ++ni)
#pragma unroll
        for (int ks = 0; ks < 2; ++ks)
          accr[mi][ni] = __builtin_amdgcn_mfma_f32_32x32x16_bf16(aL[mi][ks], prB[ni][ks], accr[mi][ni], 0, 0, 0);
    __builtin_amdgcn_s_setprio(0);

    // ---- P1: read aH; stage A(2,3) + B(0,1); S1: acci += aL*pi
#pragma unroll
    for (int mi = 0; mi < 2; ++mi)
#pragma unroll
      for (int ks = 0; ks < 2; ++ks)
        aH[mi][ks] = *(const bf16x8*)&buf[rowA[mi] + colH[ks]];
    if (pf) {
#pragma unroll
      for (int i = 0; i < 2; ++i)
        gload_lds16(srcA + (size_t)(b0 + (i + 2) * 64 + rT) * K2DIM + kp,
                    (void*)(smem + nb + (i + 2) * 4096 + dBase));
#pragma unroll
      for (int i = 0; i < 2; ++i)
        gload_lds16(srcB + (size_t)(g0 + i * 64 + rT) * N_DIM + kp,
                    (void*)(smem + nb + 16384 + i * 4096 + dBase));
    }
    LGKM(4); SB0();
    __builtin_amdgcn_s_setprio(1);
#pragma unroll
    for (int mi = 0; mi < 2; ++mi)
#pragma unroll
      for (int ni = 0; ni < 2; ++ni)
#pragma unroll
        for (int ks = 0; ks < 2; ++ks)
          acci[mi][ni] = __builtin_amdgcn_mfma_f32_32x32x16_bf16(aL[mi][ks], piB[ni][ks], acci[mi][ni], 0, 0, 0);
    __builtin_amdgcn_s_setprio(0);

    // ---- P2: prN = -prB; S2: accr += aH*pi
#pragma unroll
    for (int ni = 0; ni < 2; ++ni)
#pragma unroll
      for (int ks = 0; ks < 2; ++ks)
        prN[ni][ks] = negbf(prB[ni][ks]);
    LGKM(0); SB0();
    __builtin_amdgcn_s_setprio(1);
#pragma unroll
    for (int mi = 0; mi < 2; ++mi)
#pragma unroll
      for (int ni = 0; ni < 2; ++ni)
#pragma unroll
        for (int ks = 0; ks < 2; ++ks)
          accr[mi][ni] = __builtin_amdgcn_mfma_f32_32x32x16_bf16(aH[mi][ks], piB[ni][ks], accr[mi][ni], 0, 0, 0);
    __builtin_amdgcn_s_setprio(0);

    // ---- P3: tile boundary; pre-read next aL+prB; S3: acci += aH*(-pr)
    if (pf) {
      asm volatile("s_waitcnt vmcnt(0)" ::: "memory");
      __builtin_amdgcn_s_barrier();
      const ushort_t* bn = smem + nb;
#pragma unroll
      for (int mi = 0; mi < 2; ++mi)
#pragma unroll
        for (int ks = 0; ks < 2; ++ks)
          aL[mi][ks] = *(const bf16x8*)&bn[rowA[mi] + colL[ks]];
#pragma unroll
      for (int ni = 0; ni < 2; ++ni)
#pragma unroll
        for (int ks = 0; ks < 2; ++ks)
          prB[ni][ks] = *(const bf16x8*)&bn[rowB[ni] + colL[ks]];
      SB0();
    }
    __builtin_amdgcn_s_setprio(1);
#pragma unroll
    for (int mi = 0; mi < 2; ++mi)
#pragma unroll
      for (int ni = 0; ni < 2; ++ni)
#pragma unroll
        for (int ks = 0; ks < 2; ++ks)
          acci[mi][ni] = __builtin_amdgcn_mfma_f32_32x32x16_bf16(aH[mi][ks], prN[ni][ks], acci[mi][ni], 0, 0, 0);
    __builtin_amdgcn_s_setprio(0);
  }

  // ---- fused epilogue: per-row max (this wave's 64 cols), rowmax, candidates.
  // C/D layout: col = l&31, row = rb0 + mi*32 + (reg&3) + 8*(reg>>2), rb0 incl 4*h.
  const int rb0 = wm * 64 + 4 * h;
  const int gc0 = g0 + wn * 64 + (l & 31);
#pragma unroll
  for (int mi = 0; mi < 2; ++mi) {
    const f32x16 r0 = accr[mi][0], q0 = acci[mi][0];
    const f32x16 r1 = accr[mi][1], q1 = acci[mi][1];
#pragma unroll
    for (int reg = 0; reg < 16; ++reg) {
      const float xab0 = r0[reg] * r0[reg] + q0[reg] * q0[reg];
      const float xab1 = r1[reg] * r1[reg] + q1[reg] * q1[reg];
      float rm = fmaxf(xab0, xab1);
      rm = fmaxf(rm, __shfl_xor(rm, 1));
      rm = fmaxf(rm, __shfl_xor(rm, 2));
      rm = fmaxf(rm, __shfl_xor(rm, 4));
      rm = fmaxf(rm, __shfl_xor(rm, 8));
      rm = fmaxf(rm, __shfl_xor(rm, 16));
      const int row = b0 + rb0 + mi * 32 + (reg & 3) + 8 * (reg >> 2);
      if ((l & 31) == 0) atomicMax(&rowmax[row], __float_as_uint(rm));
      const float thrW = rm - 0.25f;
      if (xab0 >= thrW) {
        const int p = atomicAdd(&ccnt[row], 1);
        if (p < CAP) cand[(size_t)row * CAP + p] = make_int2(__float_as_int(xab0), gc0);
      }
      if (xab1 >= thrW) {
        const int p = atomicAdd(&ccnt[row], 1);
        if (p < CAP) cand[(size_t)row * CAP + p] = make_int2(__float_as_int(xab1), gc0 + 32);
      }
    }
  }
}

// ---------- K3: filter candidates by global rowmax + fp64 refine -> winner ----
__global__ __launch_bounds__(256) void k_refine(
    const unsigned* __restrict__ rowmax, const int* __restrict__ ccnt,
    const int2* __restrict__ cand, const float* __restrict__ H,
    const float* __restrict__ prT, const float* __restrict__ piT,
    int* __restrict__ wg, float* __restrict__ wxr, float* __restrict__ wxi) {
  __shared__ int scand[64];
  __shared__ int scnt;
  __shared__ double dred[8];
  const int b = blockIdx.x, tid = threadIdx.x;
  const int l = tid & 63, w = tid >> 6;
  const float thr = __uint_as_float(rowmax[b]) - 0.25f;
  int cnt = ccnt[b];
  if (cnt > CAP) cnt = CAP;
  if (tid == 0) scnt = 0;
  __syncthreads();
  for (int i = tid; i < cnt; i += 256) {
    const int2 c = cand[(size_t)b * CAP + i];
    if (__int_as_float(c.x) >= thr) {
      const int p = atomicAdd(&scnt, 1);
      if (p < 64) scand[p] = c.y;
    }
  }
  __syncthreads();
  int cc = scnt;
  if (cc > 64) cc = 64;
  double best = -1.0, bxr = 0.0, bxi = 0.0;
  int bg = 0;
  for (int ci = 0; ci < cc; ++ci) {
    const int g = scand[ci];
    double xr = 0.0, xi = 0.0;
    for (int n = tid; n < N_DIM; n += 256) {
      const double hr = H[(size_t)b * N_DIM + n];
      const double hi = H[(size_t)B_DIM * N_DIM + (size_t)b * N_DIM + n];
      const double pr = prT[(size_t)g * N_DIM + n];
      const double pi = piT[(size_t)g * N_DIM + n];
      xr += hr * pr - hi * pi;
      xi += hr * pi + hi * pr;
    }
    for (int off = 32; off; off >>= 1) {
      xr += __shfl_down(xr, off);
      xi += __shfl_down(xi, off);
    }
    if (l == 0) { dred[w * 2] = xr; dred[w * 2 + 1] = xi; }
    __syncthreads();
    if (tid == 0) {
      const double sxr = dred[0] + dred[2] + dred[4] + dred[6];
      const double sxi = dred[1] + dred[3] + dred[5] + dred[7];
      const double xab = sxr * sxr + sxi * sxi;
      if (xab > best || (xab == best && g < bg)) { best = xab; bg = g; bxr = sxr; bxi = sxi; }
    }
    __syncthreads();
  }
  if (tid == 0) { wg[b] = bg; wxr[b] = (float)bxr; wxi[b] = (float)bxi; }
}

// ---------- K4: y = winner x conj(PSI col) + zero both x planes + scatter ----
__global__ void k_y(const ushort_t* __restrict__ prBf, const ushort_t* __restrict__ piBf,
                    const int* __restrict__ wg, const float* __restrict__ wxr,
                    const float* __restrict__ wxi, float* __restrict__ out) {
  const int b = blockIdx.x, tid = threadIdx.x;
  const int g = wg[b];
  const float xr = wxr[b], xi = wxi[b];
  float* yr = out + (size_t)2 * B_DIM * G_DIM + (size_t)b * N_DIM;
  float* yi = yr + (size_t)B_DIM * N_DIM;
  const int n0 = tid * 4;
  const ushort4 p4 = *reinterpret_cast<const ushort4*>(prBf + (size_t)g * N_DIM + n0);
  const ushort4 q4 = *reinterpret_cast<const ushort4*>(piBf + (size_t)g * N_DIM + n0);
  float4 vr, vi;
  { const float pr = bf2f(p4.x), pi = bf2f(q4.x); vr.x = xr * pr + xi * pi; vi.x = xi * pr - xr * pi; }
  { const float pr = bf2f(p4.y), pi = bf2f(q4.y); vr.y = xr * pr + xi * pi; vi.y = xi * pr - xr * pi; }
  { const float pr = bf2f(p4.z), pi = bf2f(q4.z); vr.z = xr * pr + xi * pi; vi.z = xi * pr - xr * pi; }
  { const float pr = bf2f(p4.w), pi = bf2f(q4.w); vr.w = xr * pr + xi * pi; vi.w = xi * pr - xr * pi; }
  *reinterpret_cast<float4*>(yr + n0) = vr;
  *reinterpret_cast<float4*>(yi + n0) = vi;
  // zero BOTH x-plane rows b (real plane held prT/piT scratch; imag untouched)
  const float4 z = {0.f, 0.f, 0.f, 0.f};
  float* zr = out + (size_t)b * G_DIM + tid * 16;
  float* zi = out + (size_t)B_DIM * G_DIM + (size_t)b * G_DIM + tid * 16;
#pragma unroll
  for (int j = 0; j < 4; ++j) {
    *reinterpret_cast<float4*>(zr + j * 4) = z;
    *reinterpret_cast<float4*>(zi + j * 4) = z;
  }
  __syncthreads();
  if (tid == 0) {
    out[(size_t)b * G_DIM + g] = xr;                           // x real
    out[(size_t)B_DIM * G_DIM + (size_t)b * G_DIM + g] = xi;   // x imag
  }
}

extern "C" void kernel_launch(void* const* d_in, const int* in_sizes, int n_in,
                              void* d_out, int out_size, void* d_ws, size_t ws_size,
                              hipStream_t stream) {
  const float* H = (const float*)d_in[0];
  const float* theta = (const float*)d_in[1];
  const float* alpha = (const float*)d_in[2];
  float* out = (float*)d_out;
  char* ws = (char*)d_ws;

  ushort_t* prBf = (ushort_t*)(ws + WS_PRBF);
  ushort_t* piBf = (ushort_t*)(ws + WS_PIBF);
  ushort_t* hbf = (ushort_t*)(ws + WS_HBF);
  unsigned* rowmax = (unsigned*)(ws + WS_ROWMAX);
  int* ccnt = (int*)(ws + WS_CCNT);
  int2* cand = (int2*)(ws + WS_CAND);
  int* wg = (int*)(ws + WS_WG);
  float* wxr = (float*)(ws + WS_WXR);
  float* wxi = (float*)(ws + WS_WXI);

  // d_out scratch: real x-plane holds prT/piT until k_y zeroes it
  float* prT = out;                          // [G][N] f32 (16 MB)
  float* piT = out + 4194304;                // [G][N] f32 (16 MB)

  k_prep<<<8192, 256, 0, stream>>>(theta, alpha, H, prT, piT, prBf, piBf, hbf,
                                   (int4*)(ws + WS_ROWMAX));
  k_gemm<<<256, 512, 0, stream>>>(hbf, prBf, piBf, rowmax, ccnt, cand);
  k_refine<<<B_DIM, 256, 0, stream>>>(rowmax, ccnt, cand, H, prT, piT, wg, wxr, wxi);
  k_y<<<B_DIM, 256, 0, stream>>>(prBf, piBf, wg, wxr, wxi, out);  // y + zero + scatter
}

// Round 14
// 127.231 us; speedup vs baseline: 1.3943x; 1.3943x over previous
//
#include <hip/hip_runtime.h>
#include <math.h>

#define N_DIM 1024
#define G_DIM 4096
#define B_DIM 2048
#define K2DIM 2048  // 2*N (real|imag concatenated K)

typedef __attribute__((ext_vector_type(8))) short bf16x8;
typedef __attribute__((ext_vector_type(8))) unsigned short u16x8;
typedef __attribute__((ext_vector_type(16))) float f32x16;
typedef unsigned short ushort_t;

// ---------- ws layout (bytes) ----------
#define WS_PRBF  0u                      // bf16 [G][1024]   8 MB
#define WS_PIBF  (8u << 20)              // bf16 [G][1024]   8 MB
#define WS_HBF   (16u << 20)             // bf16 [B][2048]   8 MB ([Hr | -Hi])
#define WS_WG    (24u << 20)             // int [B]
#define WS_WXR   (WS_WG + 8192u)         // f32 [B]
#define WS_WXI   (WS_WXR + 8192u)        // f32 [B]

__device__ __forceinline__ unsigned short f2bf(float f) {
  unsigned u = __float_as_uint(f);
  unsigned r = u + 0x7fffu + ((u >> 16) & 1u);
  return (unsigned short)(r >> 16);
}
__device__ __forceinline__ float bf2f(unsigned short u) {
  return __uint_as_float(((unsigned)u) << 16);
}
__device__ __forceinline__ bf16x8 negbf(bf16x8 v) {
  union { bf16x8 b; uint4 u; } x;
  x.b = v;
  x.u.x ^= 0x80008000u; x.u.y ^= 0x80008000u;
  x.u.z ^= 0x80008000u; x.u.w ^= 0x80008000u;
  return x.b;
}
// fast tanh via v_exp_f32 (alpha in [0,1) -> no overflow concerns)
__device__ __forceinline__ float tanh_fast(float x) {
  const float t = __expf(2.0f * x);
  return __fdividef(t - 1.0f, t + 1.0f);
}

__device__ __forceinline__ void gload_lds16(const void* gsrc, void* ldst) {
  __builtin_amdgcn_global_load_lds(
      (const __attribute__((address_space(1))) void*)gsrc,
      (__attribute__((address_space(3))) void*)ldst, 16, 0, 0);
}

// ---------- K1: fused PSI generation + H conversion ----------
__global__ __launch_bounds__(256) void k_prep(
    const float* __restrict__ theta, const float* __restrict__ alpha,
    const float* __restrict__ H,
    float* __restrict__ prT, float* __restrict__ piT,
    ushort_t* __restrict__ prBf, ushort_t* __restrict__ piBf,
    ushort_t* __restrict__ hbf) {
  __shared__ float sp[32][33], si[32][33];
  const int bid = blockIdx.x, tid = threadIdx.x;
  if (bid < 4096) {
    // PSI part: transpose [N][G] -> [G][N], write f32 + bf16
    const int tx = tid & 31, ty = tid >> 5;
    const int g0 = (bid & 127) * 32, n0 = (bid >> 7) * 32;
    for (int rr = ty; rr < 32; rr += 8) {
      const size_t idx = (size_t)(n0 + rr) * G_DIM + g0 + tx;
      const float a = tanh_fast(alpha[idx]) * 0.03125f;  // 1/sqrt(1024)
      const float th = theta[idx];
      sp[rr][tx] = a * __cosf(th);
      si[rr][tx] = a * __sinf(th);
    }
    __syncthreads();
    for (int rr = ty; rr < 32; rr += 8) {
      const int g = g0 + rr, n = n0 + tx;
      const float pr = sp[tx][rr], pi = si[tx][rr];
      prT[(size_t)g * N_DIM + n] = pr;
      piT[(size_t)g * N_DIM + n] = pi;
      prBf[(size_t)g * N_DIM + n] = f2bf(pr);
      piBf[(size_t)g * N_DIM + n] = f2bf(pi);
    }
  } else {
    // H -> bf16, layout [B][2048] = [Hr | -Hi]
    const int j4 = ((bid - 4096) * 256 + tid) * 4;
    const int b = j4 >> 11, k = j4 & 2047, c = k >> 10, n = k & 1023;
    float4 v = *reinterpret_cast<const float4*>(
        H + (size_t)c * (B_DIM * N_DIM) + (size_t)b * N_DIM + n);
    if (c) { v.x = -v.x; v.y = -v.y; v.z = -v.z; v.w = -v.w; }
    ushort4 u;
    u.x = f2bf(v.x); u.y = f2bf(v.y); u.z = f2bf(v.z); u.w = f2bf(v.w);
    *reinterpret_cast<ushort4*>(hbf + j4) = u;
  }
}

#define LGKM(n) asm volatile("s_waitcnt lgkmcnt(" #n ")" ::: "memory")
#define SB0() __builtin_amdgcn_sched_barrier(0)

// ---------- K2: merged-B 32x32x16 dual-acc GEMM -> |x|^2 (bf16) ----------
// Best-measured core (62.8us): BM=256, BN=128, merged 32 k-lo + 32 k-hi.
// 8 waves 4M x 2N. LDS 2-ring x 48KB = 96KB; slot ^= row&7.
// accr = aL*pr + aH*pi ; acci = aL*pi + aH*(-pr)   (aH = -Hi)
__global__ __launch_bounds__(512, 2) void k_gemm(
    const ushort_t* __restrict__ hbf, const ushort_t* __restrict__ prBf,
    const ushort_t* __restrict__ piBf, ushort_t* __restrict__ xabsBf) {
  __shared__ ushort_t smem[49152];     // 96 KB: 2 bufs x 24576 ushorts
  const int tid = threadIdx.x;
  const int l = tid & 63, w = tid >> 6;
  const int wm = w >> 1, wn = w & 1;   // 4M x 2N
  const int bid = blockIdx.x;
  const int xcd = bid & 7, idx = bid >> 3;
  const int g0 = (xcd * 4 + (idx & 3)) * 128;
  const int b0 = (idx >> 2) * 256;

  // fragment offsets: rows 64 ushorts (128 B), slot ^= row&7 (row&7 == l&7)
  const int h = l >> 5;
  int colL[2], colH[2];
#pragma unroll
  for (int ks = 0; ks < 2; ++ks) {
    colL[ks] = ((ks * 2 + h) ^ (l & 7)) * 8;
    colH[ks] = ((4 + ks * 2 + h) ^ (l & 7)) * 8;
  }
  int rowA[2], rowB[2];
#pragma unroll
  for (int mi = 0; mi < 2; ++mi) rowA[mi] = (wm * 64 + mi * 32 + (l & 31)) * 64;
#pragma unroll
  for (int ni = 0; ni < 2; ++ni) rowB[ni] = 16384 + (wn * 64 + ni * 32 + (l & 31)) * 64;

  // staging: linear LDS dest, inverse-swizzled global source
  const int rT = tid >> 3, sd = tid & 7, sl = sd ^ (rT & 7);
  const ushort_t* srcA = hbf + (sl < 4 ? sl * 8 : 1024 + (sl - 4) * 8);
  const ushort_t* srcB = (sl < 4) ? (prBf + sl * 8) : (piBf + (sl - 4) * 8);
  const int dBase = (tid & ~63) * 8;

  f32x16 accr[2][2], acci[2][2];
#pragma unroll
  for (int mi = 0; mi < 2; ++mi)
#pragma unroll
    for (int ni = 0; ni < 2; ++ni) {
      accr[mi][ni] = (f32x16)(0.f);
      acci[mi][ni] = (f32x16)(0.f);
    }

  // prologue: stage tile 0 into buf 0
#pragma unroll
  for (int i = 0; i < 4; ++i)
    gload_lds16(srcA + (size_t)(b0 + i * 64 + rT) * K2DIM, (void*)(smem + i * 4096 + dBase));
#pragma unroll
  for (int i = 0; i < 2; ++i)
    gload_lds16(srcB + (size_t)(g0 + i * 64 + rT) * N_DIM, (void*)(smem + 16384 + i * 4096 + dBase));
  asm volatile("s_waitcnt vmcnt(0)" ::: "memory");
  __builtin_amdgcn_s_barrier();

  bf16x8 aL[2][2], aH[2][2], prB[2][2], piB[2][2], prN[2][2];

  // pre-read aL + prB of tile 0 (8 reads outstanding entering the loop)
  {
    const ushort_t* buf = smem;
#pragma unroll
    for (int mi = 0; mi < 2; ++mi)
#pragma unroll
      for (int ks = 0; ks < 2; ++ks)
        aL[mi][ks] = *(const bf16x8*)&buf[rowA[mi] + colL[ks]];
#pragma unroll
    for (int ni = 0; ni < 2; ++ni)
#pragma unroll
      for (int ks = 0; ks < 2; ++ks)
        prB[ni][ks] = *(const bf16x8*)&buf[rowB[ni] + colL[ks]];
  }

  for (int t = 0; t < 32; ++t) {
    const ushort_t* buf = smem + (t & 1) * 24576;
    const int nb = ((t + 1) & 1) * 24576;
    const int kp = (t + 1) * 32;
    const bool pf = (t < 31);

    // ---- P0: read piB; stage A(0,1); S0: accr += aL*pr
#pragma unroll
    for (int ni = 0; ni < 2; ++ni)
#pragma unroll
      for (int ks = 0; ks < 2; ++ks)
        piB[ni][ks] = *(const bf16x8*)&buf[rowB[ni] + colH[ks]];
    if (pf) {
#pragma unroll
      for (int i = 0; i < 2; ++i)
        gload_lds16(srcA + (size_t)(b0 + i * 64 + rT) * K2DIM + kp,
                    (void*)(smem + nb + i * 4096 + dBase));
    }
    LGKM(4); SB0();
    __builtin_amdgcn_s_setprio(1);
#pragma unroll
    for (int mi = 0; mi < 2; ++mi)
#pragma unroll
      for (int ni = 0; ni < 2; ++ni)
#pragma unroll
        for (int ks = 0; ks < 2; ++ks)
          accr[mi][ni] = __builtin_amdgcn_mfma_f32_32x32x16_bf16(aL[mi][ks], prB[ni][ks], accr[mi][ni], 0, 0, 0);
    __builtin_amdgcn_s_setprio(0);

    // ---- P1: read aH; stage A(2,3) + B(0,1); S1: acci += aL*pi
#pragma unroll
    for (int mi = 0; mi < 2; ++mi)
#pragma unroll
      for (int ks = 0; ks < 2; ++ks)
        aH[mi][ks] = *(const bf16x8*)&buf[rowA[mi] + colH[ks]];
    if (pf) {
#pragma unroll
      for (int i = 0; i < 2; ++i)
        gload_lds16(srcA + (size_t)(b0 + (i + 2) * 64 + rT) * K2DIM + kp,
                    (void*)(smem + nb + (i + 2) * 4096 + dBase));
#pragma unroll
      for (int i = 0; i < 2; ++i)
        gload_lds16(srcB + (size_t)(g0 + i * 64 + rT) * N_DIM + kp,
                    (void*)(smem + nb + 16384 + i * 4096 + dBase));
    }
    LGKM(4); SB0();
    __builtin_amdgcn_s_setprio(1);
#pragma unroll
    for (int mi = 0; mi < 2; ++mi)
#pragma unroll
      for (int ni = 0; ni < 2; ++ni)
#pragma unroll
        for (int ks = 0; ks < 2; ++ks)
          acci[mi][ni] = __builtin_amdgcn_mfma_f32_32x32x16_bf16(aL[mi][ks], piB[ni][ks], acci[mi][ni], 0, 0, 0);
    __builtin_amdgcn_s_setprio(0);

    // ---- P2: prN = -prB; S2: accr += aH*pi
#pragma unroll
    for (int ni = 0; ni < 2; ++ni)
#pragma unroll
      for (int ks = 0; ks < 2; ++ks)
        prN[ni][ks] = negbf(prB[ni][ks]);
    LGKM(0); SB0();
    __builtin_amdgcn_s_setprio(1);
#pragma unroll
    for (int mi = 0; mi < 2; ++mi)
#pragma unroll
      for (int ni = 0; ni < 2; ++ni)
#pragma unroll
        for (int ks = 0; ks < 2; ++ks)
          accr[mi][ni] = __builtin_amdgcn_mfma_f32_32x32x16_bf16(aH[mi][ks], piB[ni][ks], accr[mi][ni], 0, 0, 0);
    __builtin_amdgcn_s_setprio(0);

    // ---- P3: tile boundary; pre-read next aL+prB; S3: acci += aH*(-pr)
    if (pf) {
      asm volatile("s_waitcnt vmcnt(0)" ::: "memory");
      __builtin_amdgcn_s_barrier();
      const ushort_t* bn = smem + nb;
#pragma unroll
      for (int mi = 0; mi < 2; ++mi)
#pragma unroll
        for (int ks = 0; ks < 2; ++ks)
          aL[mi][ks] = *(const bf16x8*)&bn[rowA[mi] + colL[ks]];
#pragma unroll
      for (int ni = 0; ni < 2; ++ni)
#pragma unroll
        for (int ks = 0; ks < 2; ++ks)
          prB[ni][ks] = *(const bf16x8*)&bn[rowB[ni] + colL[ks]];
      SB0();
    }
    __builtin_amdgcn_s_setprio(1);
#pragma unroll
    for (int mi = 0; mi < 2; ++mi)
#pragma unroll
      for (int ni = 0; ni < 2; ++ni)
#pragma unroll
        for (int ks = 0; ks < 2; ++ks)
          acci[mi][ni] = __builtin_amdgcn_mfma_f32_32x32x16_bf16(aH[mi][ks], prN[ni][ks], acci[mi][ni], 0, 0, 0);
    __builtin_amdgcn_s_setprio(0);
  }

  // epilogue: |x|^2 as bf16. C/D: col=l&31, row=(reg&3)+8*(reg>>2)+4*(l>>5)
  const int rb0 = wm * 64 + 4 * (l >> 5);
#pragma unroll
  for (int mi = 0; mi < 2; ++mi)
#pragma unroll
    for (int ni = 0; ni < 2; ++ni) {
      const int gcol = g0 + wn * 64 + ni * 32 + (l & 31);
      const f32x16 r = accr[mi][ni], q = acci[mi][ni];
#pragma unroll
      for (int reg = 0; reg < 16; ++reg) {
        const int row = rb0 + mi * 32 + (reg & 3) + 8 * (reg >> 2);
        xabsBf[(size_t)(b0 + row) * G_DIM + gcol] = f2bf(r[reg] * r[reg] + q[reg] * q[reg]);
      }
    }
}

// ---------- K3: fused row-max + candidate scan + fp64 refine -> winner ----
__global__ __launch_bounds__(256) void k_scanrefine(
    const ushort_t* __restrict__ xb, const float* __restrict__ H,
    const float* __restrict__ prT, const float* __restrict__ piT,
    int* __restrict__ wg, float* __restrict__ wxr, float* __restrict__ wxi) {
  __shared__ float red[4];
  __shared__ int scnt;
  __shared__ int scand[64];
  __shared__ double dred[8];
  const int b = blockIdx.x, tid = threadIdx.x;
  const int l = tid & 63, w = tid >> 6;
  // scan phase: bf16 row (8KB), block max, candidates within 0.25 margin
  const ushort_t* row = xb + (size_t)b * G_DIM + tid * 16;
  const u16x8 u0 = *(const u16x8*)row;
  const u16x8 u1 = *(const u16x8*)(row + 8);
  float v[16];
#pragma unroll
  for (int j = 0; j < 8; ++j) { v[j] = bf2f(u0[j]); v[8 + j] = bf2f(u1[j]); }
  float m = v[0];
#pragma unroll
  for (int j = 1; j < 16; ++j) m = fmaxf(m, v[j]);
#pragma unroll
  for (int off = 32; off; off >>= 1) m = fmaxf(m, __shfl_xor(m, off));
  if (tid == 0) scnt = 0;
  if (l == 0) red[w] = m;
  __syncthreads();
  const float thr = fmaxf(fmaxf(red[0], red[1]), fmaxf(red[2], red[3])) - 0.25f;
#pragma unroll
  for (int j = 0; j < 16; ++j)
    if (v[j] >= thr) { int p = atomicAdd(&scnt, 1); if (p < 64) scand[p] = tid * 16 + j; }
  __syncthreads();
  int cnt = scnt;
  if (cnt > 64) cnt = 64;
  // refine phase: fp64 dot per candidate
  double best = -1.0, bxr = 0.0, bxi = 0.0;
  int bg = 0;
  for (int ci = 0; ci < cnt; ++ci) {
    const int g = scand[ci];
    double xr = 0.0, xi = 0.0;
    for (int n = tid; n < N_DIM; n += 256) {
      const double hr = H[(size_t)b * N_DIM + n];
      const double hi = H[(size_t)B_DIM * N_DIM + (size_t)b * N_DIM + n];
      const double pr = prT[(size_t)g * N_DIM + n];
      const double pi = piT[(size_t)g * N_DIM + n];
      xr += hr * pr - hi * pi;
      xi += hr * pi + hi * pr;
    }
    for (int off = 32; off; off >>= 1) {
      xr += __shfl_down(xr, off);
      xi += __shfl_down(xi, off);
    }
    if (l == 0) { dred[w * 2] = xr; dred[w * 2 + 1] = xi; }
    __syncthreads();
    if (tid == 0) {
      const double sxr = dred[0] + dred[2] + dred[4] + dred[6];
      const double sxi = dred[1] + dred[3] + dred[5] + dred[7];
      const double xab = sxr * sxr + sxi * sxi;
      if (xab > best || (xab == best && g < bg)) { best = xab; bg = g; bxr = sxr; bxi = sxi; }
    }
    __syncthreads();
  }
  if (tid == 0) { wg[b] = bg; wxr[b] = (float)bxr; wxi[b] = (float)bxi; }
}

// ---------- K4: y = winner x conj(PSI col) + zero both x planes + scatter ----
__global__ void k_y(const ushort_t* __restrict__ prBf, const ushort_t* __restrict__ piBf,
                    const int* __restrict__ wg, const float* __restrict__ wxr,
                    const float* __restrict__ wxi, float* __restrict__ out) {
  const int b = blockIdx.x, tid = threadIdx.x;
  const int g = wg[b];
  const float xr = wxr[b], xi = wxi[b];
  float* yr = out + (size_t)2 * B_DIM * G_DIM + (size_t)b * N_DIM;
  float* yi = yr + (size_t)B_DIM * N_DIM;
  const int n0 = tid * 4;
  const ushort4 p4 = *reinterpret_cast<const ushort4*>(prBf + (size_t)g * N_DIM + n0);
  const ushort4 q4 = *reinterpret_cast<const ushort4*>(piBf + (size_t)g * N_DIM + n0);
  float4 vr, vi;
  { const float pr = bf2f(p4.x), pi = bf2f(q4.x); vr.x = xr * pr + xi * pi; vi.x = xi * pr - xr * pi; }
  { const float pr = bf2f(p4.y), pi = bf2f(q4.y); vr.y = xr * pr + xi * pi; vi.y = xi * pr - xr * pi; }
  { const float pr = bf2f(p4.z), pi = bf2f(q4.z); vr.z = xr * pr + xi * pi; vi.z = xi * pr - xr * pi; }
  { const float pr = bf2f(p4.w), pi = bf2f(q4.w); vr.w = xr * pr + xi * pi; vi.w = xi * pr - xr * pi; }
  *reinterpret_cast<float4*>(yr + n0) = vr;
  *reinterpret_cast<float4*>(yi + n0) = vi;
  // zero BOTH x-plane rows b (real plane held prT/piT scratch; imag untouched)
  const float4 z = {0.f, 0.f, 0.f, 0.f};
  float* zr = out + (size_t)b * G_DIM + tid * 16;
  float* zi = out + (size_t)B_DIM * G_DIM + (size_t)b * G_DIM + tid * 16;
#pragma unroll
  for (int j = 0; j < 4; ++j) {
    *reinterpret_cast<float4*>(zr + j * 4) = z;
    *reinterpret_cast<float4*>(zi + j * 4) = z;
  }
  __syncthreads();
  if (tid == 0) {
    out[(size_t)b * G_DIM + g] = xr;                           // x real
    out[(size_t)B_DIM * G_DIM + (size_t)b * G_DIM + g] = xi;   // x imag
  }
}

extern "C" void kernel_launch(void* const* d_in, const int* in_sizes, int n_in,
                              void* d_out, int out_size, void* d_ws, size_t ws_size,
                              hipStream_t stream) {
  const float* H = (const float*)d_in[0];
  const float* theta = (const float*)d_in[1];
  const float* alpha = (const float*)d_in[2];
  float* out = (float*)d_out;
  char* ws = (char*)d_ws;

  ushort_t* prBf = (ushort_t*)(ws + WS_PRBF);
  ushort_t* piBf = (ushort_t*)(ws + WS_PIBF);
  ushort_t* hbf = (ushort_t*)(ws + WS_HBF);
  int* wg = (int*)(ws + WS_WG);
  float* wxr = (float*)(ws + WS_WXR);
  float* wxi = (float*)(ws + WS_WXI);

  // d_out scratch: real x-plane holds prT/piT; y-region holds bf16 xabs
  float* prT = out;                          // [G][N] f32 (16 MB)
  float* piT = out + 4194304;                // [G][N] f32 (16 MB)
  ushort_t* xabsBf = (ushort_t*)(out + 16777216);  // y-region scratch (16 MB)

  k_prep<<<8192, 256, 0, stream>>>(theta, alpha, H, prT, piT, prBf, piBf, hbf);
  k_gemm<<<256, 512, 0, stream>>>(hbf, prBf, piBf, xabsBf);
  k_scanrefine<<<B_DIM, 256, 0, stream>>>(xabsBf, H, prT, piT, wg, wxr, wxi);
  k_y<<<B_DIM, 256, 0, stream>>>(prBf, piBf, wg, wxr, wxi, out);  // y + zero + scatter
}